// Round 7
// baseline (200.405 us; speedup 1.0000x reference)
//
#include <hip/hip_runtime.h>

typedef __bf16 bf16_t;
typedef __bf16 bf16x8 __attribute__((ext_vector_type(8)));
typedef __bf16 bf16x4 __attribute__((ext_vector_type(4)));
typedef float  f32x4  __attribute__((ext_vector_type(4)));
struct uint4_t { unsigned x, y, z, w; };

#define B_  4
#define L_  4096
#define D_  1024
#define HS  64
#define NQ  192
// scale * log2(e) = 0.125 * 1.4426950408889634
#define SCL2E 0.1803368801111204f
#define MFMA16 __builtin_amdgcn_mfma_f32_16x16x32_bf16

// ---------------------------------------------------------------------------
// Kernel 1: per-block dtype detect (redundant, local) + pack W into MFMA
// B-fragment order. Block 0 publishes flags for downstream kernels.
// flags[0]: mask kind 0=int32, 1=uint8, 2=float32
// flags[1]: x/W/out are fp32 (1) vs bf16 (0)
// ---------------------------------------------------------------------------
__global__ __launch_bounds__(256) void pack_w_kernel(const void* __restrict__ Win,
                                                     const unsigned char* __restrict__ mask,
                                                     const unsigned short* __restrict__ xw,
                                                     bf16_t* __restrict__ Wtp,
                                                     int* __restrict__ flags) {
    __shared__ int c1, c23, cbad;
    int tid = threadIdx.x;
    if (tid == 0) { c1 = 0; c23 = 0; cbad = 0; }
    __syncthreads();
    uint4_t m[4];
#pragma unroll
    for (int i = 0; i < 4; ++i)
        m[i] = *(const uint4_t*)(mask + tid * 16 + i * 4096);
    int a = 0, bc = 0;
#pragma unroll
    for (int i = 0; i < 4; ++i) {
        const unsigned* w = (const unsigned*)&m[i];
#pragma unroll
        for (int j = 0; j < 4; ++j) {
            if (w[j] & 0x0000ff00u) a++;     // byte1 nonzero -> uint8 mask
            if (w[j] & 0xffff0000u) bc++;    // byte2/3 nonzero -> int32/fp32
        }
    }
    uint4_t xm = *(const uint4_t*)(xw + tid * 8);
    int bad = 0;
    const unsigned* xwv = (const unsigned*)&xm;
#pragma unroll
    for (int j = 0; j < 4; ++j)
#pragma unroll
        for (int h = 0; h < 2; ++h) {
            unsigned s = (xwv[j] >> (16 * h)) & 0xFFFFu;
            unsigned e = (s >> 7) & 0xFF;
            if (e > 150 || (e < 90 && e != 0)) bad++;
        }
    if (a)   atomicAdd(&c1, a);
    if (bc)  atomicAdd(&c23, bc);
    if (bad) atomicAdd(&cbad, bad);
    __syncthreads();
    int f32 = (cbad >= 64) ? 1 : 0;
    if (blockIdx.x == 0 && tid == 0) {
        flags[0] = (c1 > 0) ? 1 : ((c23 > 0) ? 2 : 0);
        flags[1] = f32;
    }

    // ---- pack (grid 96 x 256 = 24576 units exactly) ----
    int idx = blockIdx.x * 256 + tid;
    int lane = idx & 63;
    int t    = (idx >> 6) & 3;
    int kc   = (idx >> 8) & 31;
    int ct   = idx >> 13;
    int n  = ct * 64 + t * 16 + (lane & 15);
    int k0 = kc * 32 + (lane >> 4) * 8;
    bf16x8 v;
#pragma unroll
    for (int j = 0; j < 8; ++j) {
        if (f32) v[j] = (bf16_t)(((const float*)Win)[(k0 + j) * NQ + n]);
        else     v[j] = ((const bf16_t*)Win)[(k0 + j) * NQ + n];
    }
    *(bf16x8*)(Wtp + (size_t)idx * 8) = v;
}

// ---------------------------------------------------------------------------
// Kernel 2: QKV GEMM — barrier-free. Block = 32 rows x 192 cols, grid 512.
// Wave = 32 rows x 48 cols (3 subtiles, 2 rowgroups). A-fragments loaded
// DIRECTLY from global x (16 rows x 64B sectors per load — full sector use);
// B-fragments from L2-hot packed Wtp (1KB contiguous/wave). 2-deep register
// rotation, NO K-loop LDS or barriers — waves fully independent.
// VGPR ~85 under (256,4): no spill, deep occupancy headroom.
// ---------------------------------------------------------------------------
__global__ __launch_bounds__(256, 4) void qkv_gemm_kernel(const void* __restrict__ xin,
                                                          const int* __restrict__ flags,
                                                          const bf16_t* __restrict__ Wtp,
                                                          bf16_t* __restrict__ Qb,
                                                          bf16_t* __restrict__ Kb,
                                                          bf16_t* __restrict__ Vt) {
    __shared__ __align__(16) bf16_t sqk[32 * 136];
    __shared__ __align__(16) bf16_t sv[64 * 40];

    int tid = threadIdx.x;
    int wave = tid >> 6, lane = tid & 63, quad = lane >> 4, l16 = lane & 15;
    int ch = wave;                       // 4 waves x 48 cols = 192
    int m0 = blockIdx.x * 32;
    int xf = flags[1];

    f32x4 acc[6] = {};
    bf16x8 Aa[2], Ab[2], Ba[3], Bb[3];

    const bf16_t* xb   = (const bf16_t*)xin;
    const float*  xb32 = (const float*)xin;
    size_t rowoff0 = (size_t)(m0 + l16) * D_;
    size_t rowoff1 = (size_t)(m0 + 16 + l16) * D_;

    auto loadA = [&](int ks, bf16x8* Av) {
        int k0 = ks * 32 + quad * 8;
        if (xf) {
#pragma unroll
            for (int rg = 0; rg < 2; ++rg) {
                const float* xp = xb32 + (rg ? rowoff1 : rowoff0) + k0;
                f32x4 lo = *(const f32x4*)xp, hi = *(const f32x4*)(xp + 4);
                Av[rg][0] = (bf16_t)lo[0]; Av[rg][1] = (bf16_t)lo[1];
                Av[rg][2] = (bf16_t)lo[2]; Av[rg][3] = (bf16_t)lo[3];
                Av[rg][4] = (bf16_t)hi[0]; Av[rg][5] = (bf16_t)hi[1];
                Av[rg][6] = (bf16_t)hi[2]; Av[rg][7] = (bf16_t)hi[3];
            }
        } else {
            Av[0] = *(const bf16x8*)(xb + rowoff0 + k0);
            Av[1] = *(const bf16x8*)(xb + rowoff1 + k0);
        }
    };
    auto loadB = [&](int ks, bf16x8* Bv) {
#pragma unroll
        for (int i = 0; i < 3; ++i) {
            int st = ch * 3 + i, ct2 = st >> 2, tt = st & 3;
            Bv[i] = *(const bf16x8*)(Wtp + ((size_t)(ct2 * 32 + ks) * 4 + tt) * 512 + lane * 8);
        }
    };
    auto mm = [&](const bf16x8* Av, const bf16x8* Bv) {
#pragma unroll
        for (int i = 0; i < 3; ++i)
#pragma unroll
            for (int rg = 0; rg < 2; ++rg)
                acc[rg * 3 + i] = MFMA16(Av[rg], Bv[i], acc[rg * 3 + i], 0, 0, 0);
    };

    loadA(0, Aa); loadB(0, Ba);
    for (int ks = 0; ks < 32; ks += 2) {
        loadA(ks + 1, Ab); loadB(ks + 1, Bb);
        mm(Aa, Ba);
        int kn = (ks + 2 < 32) ? ks + 2 : 31;
        loadA(kn, Aa); loadB(kn, Ba);
        mm(Ab, Bb);
    }

    // Epilogue: stage to LDS, emit coalesced 16B stores.
#pragma unroll
    for (int i = 0; i < 3; ++i) {
        int col = ch * 48 + i * 16 + l16;
#pragma unroll
        for (int rg = 0; rg < 2; ++rg) {
            int rowb = rg * 16 + quad * 4;
#pragma unroll
            for (int r = 0; r < 4; ++r) {
                bf16_t hv = (bf16_t)acc[rg * 3 + i][r];
                if (col < 128) sqk[(rowb + r) * 136 + col] = hv;
                else           sv[(col - 128) * 40 + rowb + r] = hv;
            }
        }
    }
    __syncthreads();

    int bb = m0 >> 12, l0 = m0 & 4095;
#pragma unroll
    for (int it = 0; it < 2; ++it) {
        int c = tid + it * 256;                // 512 chunks: 32 rows x 16
        int row = c >> 4, off = (c & 15) * 8;
        bf16x8 v = *(const bf16x8*)&sqk[row * 136 + off];
        if (off < 64) *(bf16x8*)(Qb + (size_t)(bb * L_ + l0 + row) * HS + off) = v;
        else          *(bf16x8*)(Kb + (size_t)(bb * L_ + l0 + row) * HS + off - 64) = v;
    }
    {
        int d = tid >> 2, off = (tid & 3) * 8;  // 256 chunks: 64 dims x 4
        bf16x8 v = *(const bf16x8*)&sv[d * 40 + off];
        *(bf16x8*)(Vt + (size_t)(bb * HS + d) * L_ + l0 + off) = v;
    }
}

// ---------------------------------------------------------------------------
// Kernel 3: attention. Block = 128 q-rows x KCH keys; wave = 32 q-rows.
// LDS diet: ktile stride 68, P staged per-32-key-half (stride 36,
// conflict-free quad tiling), mask fp32 — 28 KB total -> 5 blocks/CU.
// K double-buffered in LDS; one barrier/iter. Rowsum via ones-MFMA.
// ---------------------------------------------------------------------------
template<int NSPLIT>
__global__ __launch_bounds__(256, 4) void attn_kernel(const bf16_t* __restrict__ Qb,
                                                      const bf16_t* __restrict__ Kb,
                                                      const bf16_t* __restrict__ Vt,
                                                      const void* __restrict__ maskp,
                                                      const int* __restrict__ flags,
                                                      float* __restrict__ Opart,
                                                      float* __restrict__ lpart,
                                                      void* __restrict__ outv) {
    constexpr int KCH = L_ / NSPLIT;
    constexpr int NIT = KCH / 64;
    __shared__ __align__(16) bf16_t ktile[2][64 * 68];
    __shared__ __align__(16) bf16_t plds[4][32 * 36];
    __shared__ float mb[KCH];

    int tid = threadIdx.x, wave = tid >> 6, lane = tid & 63;
    int quad = lane >> 4, l16 = lane & 15;
    int grp = blockIdx.x % (B_ * NSPLIT);
    int qt  = blockIdx.x / (B_ * NSPLIT);
    int s = grp / B_, b = grp % B_;
    int q0 = qt * 128;
    int kbase = s * KCH;

    const float NEGINF = -__builtin_inff();
    int mkind = flags[0];
    if (mkind == 1) {
        const unsigned char* mp = (const unsigned char*)maskp + b * L_ + kbase;
        for (int i = tid; i < KCH; i += 256) mb[i] = mp[i] ? 0.0f : NEGINF;
    } else if (mkind == 2) {
        const float* mp = (const float*)maskp + b * L_ + kbase;
        for (int i = tid; i < KCH; i += 256) mb[i] = (mp[i] != 0.0f) ? 0.0f : NEGINF;
    } else {
        const int* mp = (const int*)maskp + b * L_ + kbase;
        for (int i = tid; i < KCH; i += 256) mb[i] = mp[i] ? 0.0f : NEGINF;
    }

    bf16x8 aQ[2][2];
#pragma unroll
    for (int rg = 0; rg < 2; ++rg) {
        const bf16_t* qp = Qb + (size_t)(b * L_ + q0 + wave * 32 + rg * 16 + l16) * HS + quad * 8;
        aQ[rg][0] = *(const bf16x8*)qp;
        aQ[rg][1] = *(const bf16x8*)(qp + 32);
    }
    bf16x8 ones;
#pragma unroll
    for (int j = 0; j < 8; ++j) ones[j] = (bf16_t)1.0f;

    const bf16_t* Kbase = Kb + (size_t)b * L_ * HS;
    const bf16_t* Vbase = Vt + (size_t)b * HS * L_;

    f32x4 O[2][4] = {};
    f32x4 O5[2] = {};
    bf16_t* pw = &plds[wave][0];
    bf16x8 kr[2];

    auto kstage_load = [&](int t) {
#pragma unroll
        for (int j = 0; j < 2; ++j) {
            int c = tid + j * 256;
            int row = c >> 3, off = (c & 7) * 8;
            kr[j] = *(const bf16x8*)(Kbase + (size_t)(kbase + t * 64 + row) * HS + off);
        }
    };
    auto kstage_store = [&](int buf) {
#pragma unroll
        for (int j = 0; j < 2; ++j) {
            int c = tid + j * 256;
            int row = c >> 3, off = (c & 7) * 8;
            *(bf16x8*)&ktile[buf][row * 68 + off] = kr[j];
        }
    };

    kstage_load(0);
    kstage_store(0);
    __syncthreads();

    for (int t = 0; t < NIT; ++t) {
        int kb = kbase + t * 64;
        bool more = (t + 1 < NIT);
        if (more) kstage_load(t + 1);

        const bf16_t* kl = &ktile[t & 1][0];
#pragma unroll
        for (int h = 0; h < 2; ++h) {
            // V for this 32-key half — issued early, consumed after QK+exp
            bf16x8 V[4];
#pragma unroll
            for (int nt = 0; nt < 4; ++nt)
                V[nt] = *(const bf16x8*)(Vbase + (size_t)(nt * 16 + l16) * L_ + kb + h * 32 + quad * 8);

            f32x4 sc[2][2];
#pragma unroll
            for (int s2 = 0; s2 < 2; ++s2) {
                int st = h * 2 + s2;
                bf16x8 kb0 = *(const bf16x8*)&kl[(st * 16 + l16) * 68 + quad * 8];
                bf16x8 kb1 = *(const bf16x8*)&kl[(st * 16 + l16) * 68 + 32 + quad * 8];
#pragma unroll
                for (int rg = 0; rg < 2; ++rg) {
                    f32x4 t0 = {};
                    t0 = MFMA16(aQ[rg][0], kb0, t0, 0, 0, 0);
                    t0 = MFMA16(aQ[rg][1], kb1, t0, 0, 0, 0);
                    sc[rg][s2] = t0;
                }
            }
#pragma unroll
            for (int s2 = 0; s2 < 2; ++s2) {
                float bl = mb[t * 64 + (h * 2 + s2) * 16 + l16];
#pragma unroll
                for (int rg = 0; rg < 2; ++rg)
#pragma unroll
                    for (int r = 0; r < 4; ++r) {
                        float p = exp2f(fmaf(sc[rg][s2][r], SCL2E, bl));
                        pw[(rg * 16 + quad * 4 + r) * 36 + s2 * 16 + l16] = (bf16_t)p;
                    }
            }
            // same-wave LDS RAW: in-order per wave
#pragma unroll
            for (int rg = 0; rg < 2; ++rg) {
                bf16x8 aP = *(const bf16x8*)&pw[(rg * 16 + l16) * 36 + quad * 8];
#pragma unroll
                for (int nt = 0; nt < 4; ++nt)
                    O[rg][nt] = MFMA16(aP, V[nt], O[rg][nt], 0, 0, 0);
                O5[rg] = MFMA16(aP, ones, O5[rg], 0, 0, 0);
            }
        }

        if (more) kstage_store((t + 1) & 1);
        __syncthreads();
    }

    int of32 = flags[1];
#pragma unroll
    for (int rg = 0; rg < 2; ++rg)
#pragma unroll
        for (int r = 0; r < 4; ++r) {
            float sm = O5[rg][r];                 // rowsum from ones-MFMA
            int row = q0 + wave * 32 + rg * 16 + quad * 4 + r;
            if (NSPLIT == 1) {
                float inv = 1.0f / sm;
                size_t base = (size_t)(b * L_ + row) * HS;
                if (of32) {
                    float* op = (float*)outv + base;
#pragma unroll
                    for (int nt = 0; nt < 4; ++nt) op[nt * 16 + l16] = O[rg][nt][r] * inv;
                } else {
                    bf16_t* op = (bf16_t*)outv + base;
#pragma unroll
                    for (int nt = 0; nt < 4; ++nt) op[nt * 16 + l16] = (bf16_t)(O[rg][nt][r] * inv);
                }
            } else {
                float* op = Opart + (size_t)s * (B_ * L_ * HS) + (size_t)(b * L_ + row) * HS;
#pragma unroll
                for (int nt = 0; nt < 4; ++nt) op[nt * 16 + l16] = O[rg][nt][r];
                if (l16 == 0) lpart[(size_t)s * (B_ * L_) + b * L_ + row] = sm;
            }
        }
}

// ---------------------------------------------------------------------------
// Kernel 4: combine split-K partials, f32x4-vectorized.
// out = (sum_s O_s) / (sum_s l_s).
// ---------------------------------------------------------------------------
__global__ __launch_bounds__(256) void reduce_kernel(const float* __restrict__ Opart,
                                                     const float* __restrict__ lpart,
                                                     const int* __restrict__ flags,
                                                     void* __restrict__ outv,
                                                     int nsplit) {
    int i4 = (blockIdx.x * 256 + threadIdx.x) * 4;   // over B_*L_*HS
    int row = i4 >> 6;                                // b*L_ + l
    f32x4 acc = {};
    float lsum = 0.f;
    for (int s = 0; s < nsplit; ++s) {
        acc  += *(const f32x4*)&Opart[(size_t)s * (B_ * L_ * HS) + i4];
        lsum += lpart[(size_t)s * (B_ * L_) + row];
    }
    float inv = 1.0f / lsum;
    if (flags[1]) {
        f32x4 r = { acc[0] * inv, acc[1] * inv, acc[2] * inv, acc[3] * inv };
        *(f32x4*)&((float*)outv)[i4] = r;
    } else {
        bf16x4 r;
#pragma unroll
        for (int j = 0; j < 4; ++j) r[j] = (bf16_t)(acc[j] * inv);
        *(bf16x4*)&((bf16_t*)outv)[i4] = r;
    }
}

// ---------------------------------------------------------------------------
extern "C" void kernel_launch(void* const* d_in, const int* in_sizes, int n_in,
                              void* d_out, int out_size, void* d_ws, size_t ws_size,
                              hipStream_t stream) {
    (void)in_sizes; (void)n_in; (void)out_size;
    const void* x    = d_in[0];
    const void* mask = d_in[1];
    const void* W    = d_in[2];

    char* ws = (char*)d_ws;
    bf16_t* Qb    = (bf16_t*)(ws);                        // 2 MB
    bf16_t* Kb    = (bf16_t*)(ws + (2u << 20));           // 2 MB
    bf16_t* Vt    = (bf16_t*)(ws + (4u << 20));           // 2 MB
    bf16_t* Wtp   = (bf16_t*)(ws + (6u << 20));           // 384 KB
    int*    flags = (int*)   (ws + (6u << 20) + (512u << 10));
    float*  Opart = (float*) (ws + (7u << 20));           // nsplit * 4 MB

    auto need = [](int ns) -> size_t {
        return (7u << 20) + (size_t)ns * (B_ * L_ * HS * 4)
                          + (size_t)ns * (B_ * L_ * 4) + 4096;
    };
    int nsplit = (ws_size >= need(8)) ? 8 : (ws_size >= need(4)) ? 4 : 1;
    float* lpart = (float*)(ws + (7u << 20) + (size_t)nsplit * (B_ * L_ * HS * 4));

    pack_w_kernel<<<96, 256, 0, stream>>>(W, (const unsigned char*)mask,
                                          (const unsigned short*)x, Wtp, flags);
    qkv_gemm_kernel<<<512, 256, 0, stream>>>(x, flags, Wtp, Qb, Kb, Vt);
    if (nsplit == 8) {
        attn_kernel<8><<<32 * B_ * 8, 256, 0, stream>>>(Qb, Kb, Vt, mask, flags,
                                                        Opart, lpart, d_out);
        reduce_kernel<<<(B_ * L_ * HS) / 1024, 256, 0, stream>>>(Opart, lpart, flags,
                                                                 d_out, 8);
    } else if (nsplit == 4) {
        attn_kernel<4><<<32 * B_ * 4, 256, 0, stream>>>(Qb, Kb, Vt, mask, flags,
                                                        Opart, lpart, d_out);
        reduce_kernel<<<(B_ * L_ * HS) / 1024, 256, 0, stream>>>(Opart, lpart, flags,
                                                                 d_out, 4);
    } else {
        attn_kernel<1><<<32 * B_, 256, 0, stream>>>(Qb, Kb, Vt, mask, flags,
                                                    Opart, lpart, d_out);
    }
}

// Round 8
// 168.562 us; speedup vs baseline: 1.1889x; 1.1889x over previous
//
#include <hip/hip_runtime.h>

typedef __bf16 bf16_t;
typedef __bf16 bf16x8 __attribute__((ext_vector_type(8)));
typedef __bf16 bf16x4 __attribute__((ext_vector_type(4)));
typedef float  f32x4  __attribute__((ext_vector_type(4)));
struct uint4_t { unsigned x, y, z, w; };

typedef const __attribute__((address_space(1))) void gvoid_t;
typedef __attribute__((address_space(3))) void lvoid_t;

#define B_  4
#define L_  4096
#define D_  1024
#define HS  64
#define NQ  192
// scale * log2(e) = 0.125 * 1.4426950408889634
#define SCL2E 0.1803368801111204f
#define MFMA16 __builtin_amdgcn_mfma_f32_16x16x32_bf16

// Async 16B global->LDS DMA: lds dest = wave-uniform base + lane*16.
__device__ __forceinline__ void gld16(const void* g, void* l) {
    __builtin_amdgcn_global_load_lds((gvoid_t*)g, (lvoid_t*)l, 16, 0, 0);
}

// ---------------------------------------------------------------------------
// Kernel 1: per-block dtype detect + pack W into MFMA B-fragment order.
// flags[0]: mask kind 0=int32, 1=uint8, 2=float32
// flags[1]: x/W/out are fp32 (1) vs bf16 (0)
// ---------------------------------------------------------------------------
__global__ __launch_bounds__(256) void pack_w_kernel(const void* __restrict__ Win,
                                                     const unsigned char* __restrict__ mask,
                                                     const unsigned short* __restrict__ xw,
                                                     bf16_t* __restrict__ Wtp,
                                                     int* __restrict__ flags) {
    __shared__ int c1, c23, cbad;
    int tid = threadIdx.x;
    if (tid == 0) { c1 = 0; c23 = 0; cbad = 0; }
    __syncthreads();
    uint4_t m[4];
#pragma unroll
    for (int i = 0; i < 4; ++i)
        m[i] = *(const uint4_t*)(mask + tid * 16 + i * 4096);
    int a = 0, bc = 0;
#pragma unroll
    for (int i = 0; i < 4; ++i) {
        const unsigned* w = (const unsigned*)&m[i];
#pragma unroll
        for (int j = 0; j < 4; ++j) {
            if (w[j] & 0x0000ff00u) a++;     // byte1 nonzero -> uint8 mask
            if (w[j] & 0xffff0000u) bc++;    // byte2/3 nonzero -> int32/fp32
        }
    }
    uint4_t xm = *(const uint4_t*)(xw + tid * 8);
    int bad = 0;
    const unsigned* xwv = (const unsigned*)&xm;
#pragma unroll
    for (int j = 0; j < 4; ++j)
#pragma unroll
        for (int h = 0; h < 2; ++h) {
            unsigned s = (xwv[j] >> (16 * h)) & 0xFFFFu;
            unsigned e = (s >> 7) & 0xFF;
            if (e > 150 || (e < 90 && e != 0)) bad++;
        }
    if (a)   atomicAdd(&c1, a);
    if (bc)  atomicAdd(&c23, bc);
    if (bad) atomicAdd(&cbad, bad);
    __syncthreads();
    int f32 = (cbad >= 64) ? 1 : 0;
    if (blockIdx.x == 0 && tid == 0) {
        flags[0] = (c1 > 0) ? 1 : ((c23 > 0) ? 2 : 0);
        flags[1] = f32;
    }

    // ---- pack (grid 96 x 256 = 24576 units exactly) ----
    int idx = blockIdx.x * 256 + tid;
    int lane = idx & 63;
    int t    = (idx >> 6) & 3;
    int kc   = (idx >> 8) & 31;
    int ct   = idx >> 13;
    int n  = ct * 64 + t * 16 + (lane & 15);
    int k0 = kc * 32 + (lane >> 4) * 8;
    bf16x8 v;
#pragma unroll
    for (int j = 0; j < 8; ++j) {
        if (f32) v[j] = (bf16_t)(((const float*)Win)[(k0 + j) * NQ + n]);
        else     v[j] = ((const bf16_t*)Win)[(k0 + j) * NQ + n];
    }
    *(bf16x8*)(Wtp + (size_t)idx * 8) = v;
}

// ---------------------------------------------------------------------------
// Kernel 2: QKV GEMM (R6 wholesale-LDS structure). Block = 32 rows x 192
// cols, grid 512. x staged wholesale (2 halves, 3 barriers). Epilogue writes
// Q row-major, V transposed, and K in SWIZZLED tile-contiguous layout:
// Ksw[(b*64 + l/64)*4096 + (l%64)*64 + (g ^ (l&7))*8 .. +8]  (g = d/8)
// so attention can DMA 8KB tiles straight into unpadded LDS conflict-free.
// ---------------------------------------------------------------------------
__global__ __launch_bounds__(256, 2) void qkv_gemm_kernel(const void* __restrict__ xin,
                                                          const int* __restrict__ flags,
                                                          const bf16_t* __restrict__ Wtp,
                                                          bf16_t* __restrict__ Qb,
                                                          bf16_t* __restrict__ Ksw,
                                                          bf16_t* __restrict__ Vt) {
    __shared__ __align__(16) bf16_t xs[32 * 520];    // 32.5 KB
    __shared__ __align__(16) bf16_t sqk[32 * 136];
    __shared__ __align__(16) bf16_t sv[64 * 40];

    int tid = threadIdx.x;
    int wave = tid >> 6, lane = tid & 63, quad = lane >> 4, l16 = lane & 15;
    int rg = wave & 1, ch = wave >> 1;
    int m0 = blockIdx.x * 32;
    int xf = flags[1];

    f32x4 acc[6] = {};
    bf16x8 Ba[6], Bb[6];

    auto stage = [&](int h) {
        bf16x8 tmp[8];
#pragma unroll
        for (int j = 0; j < 8; ++j) {
            int c = tid + j * 256;
            int row = c >> 6, off = (c & 63) * 8;
            if (xf) {
                const float* xp = (const float*)xin + (size_t)(m0 + row) * D_ + h * 512 + off;
                f32x4 lo = *(const f32x4*)xp, hi = *(const f32x4*)(xp + 4);
                tmp[j][0] = (bf16_t)lo[0]; tmp[j][1] = (bf16_t)lo[1];
                tmp[j][2] = (bf16_t)lo[2]; tmp[j][3] = (bf16_t)lo[3];
                tmp[j][4] = (bf16_t)hi[0]; tmp[j][5] = (bf16_t)hi[1];
                tmp[j][6] = (bf16_t)hi[2]; tmp[j][7] = (bf16_t)hi[3];
            } else {
                tmp[j] = *(const bf16x8*)((const bf16_t*)xin + (size_t)(m0 + row) * D_ + h * 512 + off);
            }
        }
#pragma unroll
        for (int j = 0; j < 8; ++j) {
            int c = tid + j * 256;
            int row = c >> 6, off = (c & 63) * 8;
            *(bf16x8*)&xs[row * 520 + off] = tmp[j];
        }
    };
    auto loadB6 = [&](int ks, bf16x8* Bv) {
#pragma unroll
        for (int i = 0; i < 6; ++i) {
            int st = ch * 6 + i, ct2 = st >> 2, tt = st & 3;
            Bv[i] = *(const bf16x8*)(Wtp + ((size_t)(ct2 * 32 + ks) * 4 + tt) * 512 + lane * 8);
        }
    };
    auto compute6 = [&](int ks, const bf16x8* Bv) {
        bf16x8 A = *(const bf16x8*)&xs[(rg * 16 + l16) * 520 + (ks & 15) * 32 + quad * 8];
#pragma unroll
        for (int i = 0; i < 6; ++i)
            acc[i] = MFMA16(A, Bv[i], acc[i], 0, 0, 0);
    };

    stage(0);
    loadB6(0, Ba);
    __syncthreads();
#pragma unroll
    for (int half = 0; half < 2; ++half) {
        int base = half * 16;
        for (int m = 0; m < 16; m += 2) {
            int ks = base + m;
            loadB6(ks + 1, Bb);
            compute6(ks, Ba);
            loadB6(ks + 2 <= 31 ? ks + 2 : 31, Ba);
            compute6(ks + 1, Bb);
        }
        if (half == 0) {
            __syncthreads();     // everyone done reading half 0
            stage(1);
            __syncthreads();
        }
    }

    // Epilogue: stage to LDS, emit coalesced 16B stores.
    int rowb = rg * 16 + quad * 4;
#pragma unroll
    for (int i = 0; i < 6; ++i) {
        int col = ch * 96 + i * 16 + l16;
#pragma unroll
        for (int r = 0; r < 4; ++r) {
            bf16_t hv = (bf16_t)acc[i][r];
            if (col < 128) sqk[(rowb + r) * 136 + col] = hv;
            else           sv[(col - 128) * 40 + rowb + r] = hv;
        }
    }
    __syncthreads();

    int bb = m0 >> 12, l0 = m0 & 4095;
#pragma unroll
    for (int it = 0; it < 2; ++it) {
        int c = tid + it * 256;                // 512 chunks: 32 rows x 16
        int row = c >> 4, off = (c & 15) * 8;
        bf16x8 v = *(const bf16x8*)&sqk[row * 136 + off];
        if (off < 64) {
            *(bf16x8*)(Qb + (size_t)(bb * L_ + l0 + row) * HS + off) = v;
        } else {
            int l = l0 + row;
            int g = (off >> 3) - 8;            // K col group 0..7
            int gp = g ^ (l & 7);              // bank swizzle baked into global
            *(bf16x8*)(Ksw + (size_t)(bb * 64 + (l >> 6)) * 4096
                           + (size_t)(l & 63) * 64 + gp * 8) = v;
        }
    }
    {
        int d = tid >> 2, off = (tid & 3) * 8;  // 256 chunks: 64 dims x 4
        bf16x8 v = *(const bf16x8*)&sv[d * 40 + off];
        *(bf16x8*)(Vt + (size_t)(bb * HS + d) * L_ + l0 + off) = v;
    }
}

// ---------------------------------------------------------------------------
// Kernel 3: attention (R6 structure + async K staging). Block = 128 q-rows,
// wave = 32 q-rows. K tiles (8KB, swizzled global layout) DMA'd via
// global_load_lds into unpadded double-buffered LDS: the DMA for tile t+1 is
// issued at the TOP of iteration t, so the barrier's vmcnt(0) drain has a
// full iteration of latency cover (the m93->m97 mechanism). Swizzled reads
// are conflict-free. Rowsum via ones-MFMA. P round-trip per 64-key tile.
// ---------------------------------------------------------------------------
template<int NSPLIT>
__global__ __launch_bounds__(256, 4) void attn_kernel(const bf16_t* __restrict__ Qb,
                                                      const bf16_t* __restrict__ Ksw,
                                                      const bf16_t* __restrict__ Vt,
                                                      const void* __restrict__ maskp,
                                                      const int* __restrict__ flags,
                                                      float* __restrict__ Opart,
                                                      float* __restrict__ lpart,
                                                      void* __restrict__ outv) {
    constexpr int KCH = L_ / NSPLIT;
    constexpr int NIT = KCH / 64;
    __shared__ __align__(16) bf16_t ktile[2][64 * 64];   // unpadded, swizzled
    __shared__ __align__(16) bf16_t plds[4][32 * 72];
    __shared__ float mb[KCH];

    int tid = threadIdx.x, wave = tid >> 6, lane = tid & 63;
    int quad = lane >> 4, l16 = lane & 15;
    int grp = blockIdx.x % (B_ * NSPLIT);
    int qt  = blockIdx.x / (B_ * NSPLIT);
    int s = grp / B_, b = grp % B_;
    int q0 = qt * 128;
    int kbase = s * KCH;

    // Async DMA of K tile t into buf: 8KB = 512 chunks; each wave issues 2
    // (wave-uniform LDS base, per-lane global addr, lane*16 placement).
    const bf16_t* Ktiles = Ksw + (size_t)(b * 64 + (kbase >> 6)) * 4096;
    auto kdma = [&](int t, int buf) {
        const bf16_t* g = Ktiles + (size_t)t * 4096;
#pragma unroll
        for (int j = 0; j < 2; ++j) {
            int cbase = wave * 64 + j * 256;
            gld16(g + (size_t)(cbase + lane) * 8, &ktile[buf][cbase * 8]);
        }
    };

    kdma(0, 0);

    const float NEGINF = -__builtin_inff();
    int mkind = flags[0];
    if (mkind == 1) {
        const unsigned char* mp = (const unsigned char*)maskp + b * L_ + kbase;
        for (int i = tid; i < KCH; i += 256) mb[i] = mp[i] ? 0.0f : NEGINF;
    } else if (mkind == 2) {
        const float* mp = (const float*)maskp + b * L_ + kbase;
        for (int i = tid; i < KCH; i += 256) mb[i] = (mp[i] != 0.0f) ? 0.0f : NEGINF;
    } else {
        const int* mp = (const int*)maskp + b * L_ + kbase;
        for (int i = tid; i < KCH; i += 256) mb[i] = mp[i] ? 0.0f : NEGINF;
    }

    bf16x8 aQ[2][2];
#pragma unroll
    for (int rg = 0; rg < 2; ++rg) {
        const bf16_t* qp = Qb + (size_t)(b * L_ + q0 + wave * 32 + rg * 16 + l16) * HS + quad * 8;
        aQ[rg][0] = *(const bf16x8*)qp;
        aQ[rg][1] = *(const bf16x8*)(qp + 32);
    }
    bf16x8 ones;
#pragma unroll
    for (int j = 0; j < 8; ++j) ones[j] = (bf16_t)1.0f;

    const bf16_t* Vbase = Vt + (size_t)b * HS * L_;

    f32x4 O[2][4] = {};
    f32x4 O5[2] = {};
    bf16_t* pw = &plds[wave][0];

    // swizzled read groups: logical col group g ^ (row&7); row&7 == l16&7
    int rph = l16 & 7;
    int g0 = (quad ^ rph) * 8;
    int g1 = ((quad + 4) ^ rph) * 8;

    __syncthreads();   // mb visible + tile 0 DMA drained

    for (int t = 0; t < NIT; ++t) {
        int kb = kbase + t * 64;
        bool more = (t + 1 < NIT);
        if (more) kdma(t + 1, (t + 1) & 1);   // issued now, waited at barrier

        // V first half (keys kb..kb+31) — hidden under QK + exp
        bf16x8 V0[4];
#pragma unroll
        for (int nt = 0; nt < 4; ++nt)
            V0[nt] = *(const bf16x8*)(Vbase + (size_t)(nt * 16 + l16) * L_ + kb + quad * 8);

        const bf16_t* kl = &ktile[t & 1][0];
#pragma unroll
        for (int h = 0; h < 2; ++h) {
            f32x4 sc[2][2];
#pragma unroll
            for (int s2 = 0; s2 < 2; ++s2) {
                int st = h * 2 + s2;
                int rbase = (st * 16 + l16) * 64;
                bf16x8 kb0 = *(const bf16x8*)&kl[rbase + g0];
                bf16x8 kb1 = *(const bf16x8*)&kl[rbase + g1];
#pragma unroll
                for (int rg = 0; rg < 2; ++rg) {
                    f32x4 t0 = {};
                    t0 = MFMA16(aQ[rg][0], kb0, t0, 0, 0, 0);
                    t0 = MFMA16(aQ[rg][1], kb1, t0, 0, 0, 0);
                    sc[rg][s2] = t0;
                }
            }
#pragma unroll
            for (int s2 = 0; s2 < 2; ++s2) {
                int st = h * 2 + s2;
                float bl = mb[t * 64 + st * 16 + l16];
#pragma unroll
                for (int rg = 0; rg < 2; ++rg)
#pragma unroll
                    for (int r = 0; r < 4; ++r) {
                        float p = exp2f(fmaf(sc[rg][s2][r], SCL2E, bl));
                        pw[(rg * 16 + quad * 4 + r) * 72 + st * 16 + l16] = (bf16_t)p;
                    }
            }
        }

        // P c=0 read + PV + rowsum (same-wave LDS RAW: in-order per wave)
#pragma unroll
        for (int rg = 0; rg < 2; ++rg) {
            bf16x8 aP = *(const bf16x8*)&pw[(rg * 16 + l16) * 72 + quad * 8];
#pragma unroll
            for (int nt = 0; nt < 4; ++nt)
                O[rg][nt] = MFMA16(aP, V0[nt], O[rg][nt], 0, 0, 0);
            O5[rg] = MFMA16(aP, ones, O5[rg], 0, 0, 0);
        }
        // V second half + PV + rowsum
        bf16x8 V1[4];
#pragma unroll
        for (int nt = 0; nt < 4; ++nt)
            V1[nt] = *(const bf16x8*)(Vbase + (size_t)(nt * 16 + l16) * L_ + kb + 32 + quad * 8);
#pragma unroll
        for (int rg = 0; rg < 2; ++rg) {
            bf16x8 aP = *(const bf16x8*)&pw[(rg * 16 + l16) * 72 + 32 + quad * 8];
#pragma unroll
            for (int nt = 0; nt < 4; ++nt)
                O[rg][nt] = MFMA16(aP, V1[nt], O[rg][nt], 0, 0, 0);
            O5[rg] = MFMA16(aP, ones, O5[rg], 0, 0, 0);
        }

        __syncthreads();   // drains this iter's DMA (issued a full iter ago)
    }

    int of32 = flags[1];
#pragma unroll
    for (int rg = 0; rg < 2; ++rg)
#pragma unroll
        for (int r = 0; r < 4; ++r) {
            float sm = O5[rg][r];                 // rowsum from ones-MFMA
            int row = q0 + wave * 32 + rg * 16 + quad * 4 + r;
            if (NSPLIT == 1) {
                float inv = 1.0f / sm;
                size_t base = (size_t)(b * L_ + row) * HS;
                if (of32) {
                    float* op = (float*)outv + base;
#pragma unroll
                    for (int nt = 0; nt < 4; ++nt) op[nt * 16 + l16] = O[rg][nt][r] * inv;
                } else {
                    bf16_t* op = (bf16_t*)outv + base;
#pragma unroll
                    for (int nt = 0; nt < 4; ++nt) op[nt * 16 + l16] = (bf16_t)(O[rg][nt][r] * inv);
                }
            } else {
                float* op = Opart + (size_t)s * (B_ * L_ * HS) + (size_t)(b * L_ + row) * HS;
#pragma unroll
                for (int nt = 0; nt < 4; ++nt) op[nt * 16 + l16] = O[rg][nt][r];
                if (l16 == 0) lpart[(size_t)s * (B_ * L_) + b * L_ + row] = sm;
            }
        }
}

// ---------------------------------------------------------------------------
// Kernel 4: combine split-K partials, f32x4-vectorized.
// ---------------------------------------------------------------------------
__global__ __launch_bounds__(256) void reduce_kernel(const float* __restrict__ Opart,
                                                     const float* __restrict__ lpart,
                                                     const int* __restrict__ flags,
                                                     void* __restrict__ outv,
                                                     int nsplit) {
    int i4 = (blockIdx.x * 256 + threadIdx.x) * 4;   // over B_*L_*HS
    int row = i4 >> 6;                                // b*L_ + l
    f32x4 acc = {};
    float lsum = 0.f;
    for (int s = 0; s < nsplit; ++s) {
        acc  += *(const f32x4*)&Opart[(size_t)s * (B_ * L_ * HS) + i4];
        lsum += lpart[(size_t)s * (B_ * L_) + row];
    }
    float inv = 1.0f / lsum;
    if (flags[1]) {
        f32x4 r = { acc[0] * inv, acc[1] * inv, acc[2] * inv, acc[3] * inv };
        *(f32x4*)&((float*)outv)[i4] = r;
    } else {
        bf16x4 r;
#pragma unroll
        for (int j = 0; j < 4; ++j) r[j] = (bf16_t)(acc[j] * inv);
        *(bf16x4*)&((bf16_t*)outv)[i4] = r;
    }
}

// ---------------------------------------------------------------------------
extern "C" void kernel_launch(void* const* d_in, const int* in_sizes, int n_in,
                              void* d_out, int out_size, void* d_ws, size_t ws_size,
                              hipStream_t stream) {
    (void)in_sizes; (void)n_in; (void)out_size;
    const void* x    = d_in[0];
    const void* mask = d_in[1];
    const void* W    = d_in[2];

    char* ws = (char*)d_ws;
    bf16_t* Qb    = (bf16_t*)(ws);                        // 2 MB
    bf16_t* Ksw   = (bf16_t*)(ws + (2u << 20));           // 2 MB (swizzled tiles)
    bf16_t* Vt    = (bf16_t*)(ws + (4u << 20));           // 2 MB
    bf16_t* Wtp   = (bf16_t*)(ws + (6u << 20));           // 384 KB
    int*    flags = (int*)   (ws + (6u << 20) + (512u << 10));
    float*  Opart = (float*) (ws + (7u << 20));           // nsplit * 4 MB

    auto need = [](int ns) -> size_t {
        return (7u << 20) + (size_t)ns * (B_ * L_ * HS * 4)
                          + (size_t)ns * (B_ * L_ * 4) + 4096;
    };
    int nsplit = (ws_size >= need(8)) ? 8 : (ws_size >= need(4)) ? 4 : 1;
    float* lpart = (float*)(ws + (7u << 20) + (size_t)nsplit * (B_ * L_ * HS * 4));

    pack_w_kernel<<<96, 256, 0, stream>>>(W, (const unsigned char*)mask,
                                          (const unsigned short*)x, Wtp, flags);
    qkv_gemm_kernel<<<512, 256, 0, stream>>>(x, flags, Wtp, Qb, Ksw, Vt);
    if (nsplit == 8) {
        attn_kernel<8><<<32 * B_ * 8, 256, 0, stream>>>(Qb, Ksw, Vt, mask, flags,
                                                        Opart, lpart, d_out);
        reduce_kernel<<<(B_ * L_ * HS) / 1024, 256, 0, stream>>>(Opart, lpart, flags,
                                                                 d_out, 8);
    } else if (nsplit == 4) {
        attn_kernel<4><<<32 * B_ * 4, 256, 0, stream>>>(Qb, Ksw, Vt, mask, flags,
                                                        Opart, lpart, d_out);
        reduce_kernel<<<(B_ * L_ * HS) / 1024, 256, 0, stream>>>(Opart, lpart, flags,
                                                                 d_out, 4);
    } else {
        attn_kernel<1><<<32 * B_, 256, 0, stream>>>(Qb, Ksw, Vt, mask, flags,
                                                    Opart, lpart, d_out);
    }
}